// Round 10
// baseline (310.480 us; speedup 1.0000x reference)
//
#include <hip/hip_runtime.h>
#include <hip/hip_bf16.h>

// GAT layer: N=50000, E=800000, IN=128, OUT=256, HEADS=8, C=32
// R10: exact R8 structure (proven passing, 308us) with ONE change:
// gather inner loop processes 4 edges/iteration with uniform shfl indices
// (independent register chains -> 4 gather loads in flight per lane).
//
// ws layout:
//   hb    : N*256 u16 (bf16 h)
//   Bt    : 512*128 u16 (bf16 [W | resW^T] transposed: Bt[j][k])
//   a_src : N*8 f32
//   a_dst : N*8 f32
//   deg   : N int (cursor)
//   rowptr: (N+1) int
//   parts : 256 int
//   col   : E int
// identity lives in d_out (f32), overwritten in place by gather_finalize.

typedef __attribute__((ext_vector_type(8))) __bf16 v8bf;
typedef __attribute__((ext_vector_type(4))) float  v4f;

__device__ __forceinline__ float bf2f(unsigned short u) {
    return __uint_as_float(((unsigned int)u) << 16);
}
__device__ __forceinline__ unsigned short f2bf(float f) {   // RNE
    unsigned int u = __float_as_uint(f);
    u = u + 0x7FFFu + ((u >> 16) & 1u);
    return (unsigned short)(u >> 16);
}

// ---- pack Bt[j][k] = bf16( j<256 ? W[k][j] : resW[j-256][k] ) ----
__global__ __launch_bounds__(256) void pack_Bt_kernel(const float* __restrict__ W,
                                                      const float* __restrict__ resW,
                                                      unsigned short* __restrict__ Bt) {
    int id = blockIdx.x * 256 + threadIdx.x;   // 0..65535
    int j = id >> 7;          // 0..511
    int k = id & 127;
    float v = (j < 256) ? W[k * 256 + j] : resW[(size_t)(j - 256) * 128 + k];
    Bt[id] = f2bf(v);
}

// ---- fused MFMA GEMM + att logits (unchanged from R8) ----
__global__ __launch_bounds__(256) void mfma_gemm_kernel(const float* __restrict__ x,
                                                        const unsigned short* __restrict__ Bt,
                                                        const float* __restrict__ att_src,
                                                        const float* __restrict__ att_dst,
                                                        const float* __restrict__ res_b,
                                                        unsigned short* __restrict__ hb,
                                                        float* __restrict__ iden,
                                                        float* __restrict__ a_src,
                                                        float* __restrict__ a_dst,
                                                        int N_) {
    __shared__ unsigned short As[64][136];
    __shared__ unsigned short Bs[64][136];
    __shared__ float Cs[64][68];
    const int tid = threadIdx.x;
    const int brow = blockIdx.x * 64;

    #pragma unroll
    for (int it = 0; it < 4; ++it) {
        int cid = it * 256 + tid;
        int row = cid >> 4;
        int c   = cid & 15;
        int grow = brow + row;
        unsigned int w[4];
        if (grow < N_) {
            const float4* xp = (const float4*)(x + (size_t)grow * 128 + c * 8);
            float4 v0 = xp[0], v1 = xp[1];
            w[0] = (unsigned)f2bf(v0.x) | ((unsigned)f2bf(v0.y) << 16);
            w[1] = (unsigned)f2bf(v0.z) | ((unsigned)f2bf(v0.w) << 16);
            w[2] = (unsigned)f2bf(v1.x) | ((unsigned)f2bf(v1.y) << 16);
            w[3] = (unsigned)f2bf(v1.z) | ((unsigned)f2bf(v1.w) << 16);
        } else {
            w[0] = w[1] = w[2] = w[3] = 0u;
        }
        *(int4*)&As[row][c * 8] = make_int4(w[0], w[1], w[2], w[3]);
    }

    const int lane = tid & 63;
    const int wid  = tid >> 6;
    const int wm = wid & 1;
    const int wn = wid >> 1;
    const int lm = lane & 15;
    const int lk = lane >> 4;

    const int tRow = tid >> 2;
    const int tcc  = (tid & 3) * 16;

    v8bf afr[4][2];
    bool afr_loaded = false;

    #pragma unroll 1
    for (int bc = 0; bc < 8; ++bc) {
        #pragma unroll
        for (int it = 0; it < 4; ++it) {
            int cid = it * 256 + tid;
            int row = cid >> 4;
            int c   = cid & 15;
            *(int4*)&Bs[row][c * 8] =
                *(const int4*)(Bt + (size_t)(bc * 64 + row) * 128 + c * 8);
        }
        __syncthreads();

        if (!afr_loaded) {
            afr_loaded = true;
            #pragma unroll
            for (int ks = 0; ks < 4; ++ks) {
                int koff = ks * 32 + lk * 8;
                afr[ks][0] = *(const v8bf*)&As[wm * 32 + lm][koff];
                afr[ks][1] = *(const v8bf*)&As[wm * 32 + 16 + lm][koff];
            }
        }

        v4f acc[2][2] = {};
        #pragma unroll
        for (int ks = 0; ks < 4; ++ks) {
            int koff = ks * 32 + lk * 8;
            v8bf b0 = *(const v8bf*)&Bs[wn * 32 + lm][koff];
            v8bf b1 = *(const v8bf*)&Bs[wn * 32 + 16 + lm][koff];
            acc[0][0] = __builtin_amdgcn_mfma_f32_16x16x32_bf16(afr[ks][0], b0, acc[0][0], 0, 0, 0);
            acc[0][1] = __builtin_amdgcn_mfma_f32_16x16x32_bf16(afr[ks][0], b1, acc[0][1], 0, 0, 0);
            acc[1][0] = __builtin_amdgcn_mfma_f32_16x16x32_bf16(afr[ks][1], b0, acc[1][0], 0, 0, 0);
            acc[1][1] = __builtin_amdgcn_mfma_f32_16x16x32_bf16(afr[ks][1], b1, acc[1][1], 0, 0, 0);
        }

        // C/D layout (m89-verified): col = lane&15, row = (lane>>4)*4 + reg
        #pragma unroll
        for (int i = 0; i < 2; ++i)
            #pragma unroll
            for (int j = 0; j < 2; ++j)
                #pragma unroll
                for (int r = 0; r < 4; ++r)
                    Cs[wm * 32 + i * 16 + lk * 4 + r][wn * 32 + j * 16 + lm] = acc[i][j][r];
        __syncthreads();

        int grow = brow + tRow;
        if (grow < N_) {
            int gcol = bc * 64 + tcc;
            float vs[16];
            #pragma unroll
            for (int q = 0; q < 4; ++q) {
                float4 t4 = *(const float4*)&Cs[tRow][tcc + q * 4];
                vs[q * 4 + 0] = t4.x; vs[q * 4 + 1] = t4.y;
                vs[q * 4 + 2] = t4.z; vs[q * 4 + 3] = t4.w;
            }
            if (gcol < 256) {
                int head = gcol >> 5;
                int chb  = gcol & 31;
                float ps = 0.f, pd = 0.f;
                #pragma unroll
                for (int c = 0; c < 16; ++c) {
                    ps += vs[c] * att_src[head * 32 + chb + c];
                    pd += vs[c] * att_dst[head * 32 + chb + c];
                }
                ps += __shfl_xor(ps, 1);
                pd += __shfl_xor(pd, 1);
                if (!(tid & 1)) {
                    a_src[grow * 8 + head] = ps;
                    a_dst[grow * 8 + head] = pd;
                }
                unsigned int w[8];
                #pragma unroll
                for (int c = 0; c < 8; ++c)
                    w[c] = (unsigned)f2bf(vs[2 * c]) | ((unsigned)f2bf(vs[2 * c + 1]) << 16);
                unsigned short* hp = hb + (size_t)grow * 256 + gcol;
                *(int4*)hp       = make_int4(w[0], w[1], w[2], w[3]);
                *(int4*)(hp + 8) = make_int4(w[4], w[5], w[6], w[7]);
            } else {
                int oc = gcol - 256;
                float* ip = iden + (size_t)grow * 256 + oc;
                #pragma unroll
                for (int q = 0; q < 4; ++q) {
                    float4 v = make_float4(vs[q * 4 + 0], vs[q * 4 + 1],
                                           vs[q * 4 + 2], vs[q * 4 + 3]);
                    const float4 rb = *(const float4*)(res_b + oc + q * 4);
                    v.x += rb.x; v.y += rb.y; v.z += rb.z; v.w += rb.w;
                    *(float4*)(ip + q * 4) = v;
                }
            }
        }
        __syncthreads();
    }
}

// ---- CSR build (exact R8 three-kernel scan) ----
__global__ __launch_bounds__(256) void hist_kernel(const int* __restrict__ ei,
                                                   int* __restrict__ deg, int E_, int N_) {
    int i = blockIdx.x * 256 + threadIdx.x;
    if (i >= E_) return;
    int d = ei[E_ + i];
    if ((unsigned)d < (unsigned)N_) atomicAdd(&deg[d], 1);
}

__global__ __launch_bounds__(256) void scan_part_kernel(const int* __restrict__ deg,
                                                        int* __restrict__ partials,
                                                        int N_) {
    __shared__ int tmp[256];
    int i = blockIdx.x * 256 + threadIdx.x;
    int v = (i < N_) ? deg[i] : 0;
    tmp[threadIdx.x] = v;
    __syncthreads();
    for (int off = 128; off >= 1; off >>= 1) {
        if (threadIdx.x < off) tmp[threadIdx.x] += tmp[threadIdx.x + off];
        __syncthreads();
    }
    if (threadIdx.x == 0) partials[blockIdx.x] = tmp[0];
}

__global__ __launch_bounds__(256) void scan_top_kernel(int* __restrict__ partials, int nparts) {
    __shared__ int tmp[256];
    int t = threadIdx.x;
    int v = (t < nparts) ? partials[t] : 0;
    tmp[t] = v;
    __syncthreads();
    for (int off = 1; off < 256; off <<= 1) {
        int x = (t >= off) ? tmp[t - off] : 0;
        __syncthreads();
        tmp[t] += x;
        __syncthreads();
    }
    if (t < nparts) partials[t] = tmp[t] - v;   // exclusive
}

__global__ __launch_bounds__(256) void scan_final_kernel(int* __restrict__ deg,
                                                         const int* __restrict__ partials,
                                                         int* __restrict__ rowptr,
                                                         int N_) {
    __shared__ int tmp[256];
    int t = threadIdx.x;
    int i = blockIdx.x * 256 + t;
    int v = (i < N_) ? deg[i] : 0;
    tmp[t] = v;
    __syncthreads();
    for (int off = 1; off < 256; off <<= 1) {
        int x = (t >= off) ? tmp[t - off] : 0;
        __syncthreads();
        tmp[t] += x;
        __syncthreads();
    }
    int excl = tmp[t] - v + partials[blockIdx.x];
    if (i < N_) {
        rowptr[i] = excl;
        deg[i] = excl;                 // cursor
        if (i == N_ - 1) rowptr[N_] = excl + v;
    }
}

__global__ __launch_bounds__(256) void scatter_kernel(const int* __restrict__ ei,
                                                      int* __restrict__ cursor,
                                                      int* __restrict__ col,
                                                      int E_, int N_) {
    int i = blockIdx.x * 256 + threadIdx.x;
    if (i >= E_) return;
    int s = ei[i];
    int d = ei[E_ + i];
    if ((unsigned)s >= (unsigned)N_ || (unsigned)d >= (unsigned)N_) return;
    int pos = atomicAdd(&cursor[d], 1);
    col[pos] = s;
}

// ---- gather + finalize: R8 lane semantics (lane -> 4 channels, hd = lane>>3),
// inner loop unrolled 4 edges/iter with UNIFORM shfl indices + scalar tail. ----
__global__ __launch_bounds__(256) void gather_finalize_kernel(
        const int* __restrict__ rowptr, const int* __restrict__ col,
        const unsigned short* __restrict__ hb,
        const float* __restrict__ a_src, const float* __restrict__ a_dst,
        const float* __restrict__ bias, const float* __restrict__ gamma,
        const float* __restrict__ beta,
        float* __restrict__ out, int N_) {
    int n = blockIdx.x * 4 + (threadIdx.x >> 6);
    if (n >= N_) return;
    int lane = threadIdx.x & 63;
    int hd = lane >> 3;                 // head for this lane's 4 channels (f = lane*4)

    float adst = a_dst[n * 8 + hd];

    // self loop
    float es = a_src[n * 8 + hd] + adst;
    es = es > 0.f ? es : 0.2f * es;
    float w = __expf(es);
    ushort4 hv = *(const ushort4*)(hb + (size_t)n * 256 + lane * 4);
    float accx = w * bf2f(hv.x), accy = w * bf2f(hv.y);
    float accz = w * bf2f(hv.z), accw = w * bf2f(hv.w);
    float wsum = w;

    int beg = rowptr[n], end = rowptr[n + 1];
    for (int e0 = beg; e0 < end; e0 += 64) {
        int myc = (e0 + lane < end) ? col[e0 + lane] : 0;
        int cnt = min(64, end - e0);
        int j = 0;
        for (; j + 3 < cnt; j += 4) {
            int s0 = __shfl(myc, j);
            int s1 = __shfl(myc, j + 1);
            int s2 = __shfl(myc, j + 2);
            int s3 = __shfl(myc, j + 3);
            float e0f = a_src[s0 * 8 + hd] + adst;
            float e1f = a_src[s1 * 8 + hd] + adst;
            float e2f = a_src[s2 * 8 + hd] + adst;
            float e3f = a_src[s3 * 8 + hd] + adst;
            e0f = e0f > 0.f ? e0f : 0.2f * e0f;
            e1f = e1f > 0.f ? e1f : 0.2f * e1f;
            e2f = e2f > 0.f ? e2f : 0.2f * e2f;
            e3f = e3f > 0.f ? e3f : 0.2f * e3f;
            float w0 = __expf(e0f);
            float w1 = __expf(e1f);
            float w2 = __expf(e2f);
            float w3 = __expf(e3f);
            ushort4 h0 = *(const ushort4*)(hb + (size_t)s0 * 256 + lane * 4);
            ushort4 h1 = *(const ushort4*)(hb + (size_t)s1 * 256 + lane * 4);
            ushort4 h2 = *(const ushort4*)(hb + (size_t)s2 * 256 + lane * 4);
            ushort4 h3 = *(const ushort4*)(hb + (size_t)s3 * 256 + lane * 4);
            accx += w0 * bf2f(h0.x) + w1 * bf2f(h1.x) + w2 * bf2f(h2.x) + w3 * bf2f(h3.x);
            accy += w0 * bf2f(h0.y) + w1 * bf2f(h1.y) + w2 * bf2f(h2.y) + w3 * bf2f(h3.y);
            accz += w0 * bf2f(h0.z) + w1 * bf2f(h1.z) + w2 * bf2f(h2.z) + w3 * bf2f(h3.z);
            accw += w0 * bf2f(h0.w) + w1 * bf2f(h1.w) + w2 * bf2f(h2.w) + w3 * bf2f(h3.w);
            wsum += (w0 + w1) + (w2 + w3);
        }
        for (; j < cnt; ++j) {
            int s = __shfl(myc, j);
            float ea = a_src[s * 8 + hd] + adst;
            ea = ea > 0.f ? ea : 0.2f * ea;
            float we = __expf(ea);
            ushort4 hs = *(const ushort4*)(hb + (size_t)s * 256 + lane * 4);
            accx += we * bf2f(hs.x); accy += we * bf2f(hs.y);
            accz += we * bf2f(hs.z); accw += we * bf2f(hs.w);
            wsum += we;
        }
    }

    float inv_w = 1.f / (wsum + 1e-16f);
    float4 b4 = *(const float4*)(bias + lane * 4);
    float v0 = accx * inv_w + b4.x;
    float v1 = accy * inv_w + b4.y;
    float v2 = accz * inv_w + b4.z;
    float v3 = accw * inv_w + b4.w;

    float sum = v0 + v1 + v2 + v3;
    float sumsq = v0 * v0 + v1 * v1 + v2 * v2 + v3 * v3;
    #pragma unroll
    for (int o = 32; o >= 1; o >>= 1) {
        sum   += __shfl_xor(sum, o);
        sumsq += __shfl_xor(sumsq, o);
    }
    float mean = sum * (1.f / 256.f);
    float var  = sumsq * (1.f / 256.f) - mean * mean;
    float inv  = rsqrtf(var + 1e-5f);

    float4 g4  = *(const float4*)(gamma + lane * 4);
    float4 be4 = *(const float4*)(beta + lane * 4);
    float4 id4 = *(const float4*)(out + (size_t)n * 256 + lane * 4);

    float y0 = g4.x * (v0 - mean) * inv + be4.x + id4.x;
    float y1 = g4.y * (v1 - mean) * inv + be4.y + id4.y;
    float y2 = g4.z * (v2 - mean) * inv + be4.z + id4.z;
    float y3 = g4.w * (v3 - mean) * inv + be4.w + id4.w;
    float4 r;
    r.x = y0 > 0.f ? y0 : (__expf(y0) - 1.f);
    r.y = y1 > 0.f ? y1 : (__expf(y1) - 1.f);
    r.z = y2 > 0.f ? y2 : (__expf(y2) - 1.f);
    r.w = y3 > 0.f ? y3 : (__expf(y3) - 1.f);
    *(float4*)(out + (size_t)n * 256 + lane * 4) = r;
}

extern "C" void kernel_launch(void* const* d_in, const int* in_sizes, int n_in,
                              void* d_out, int out_size, void* d_ws, size_t ws_size,
                              hipStream_t stream) {
    const float* x       = (const float*)d_in[0];
    const int*   ei      = (const int*)d_in[1];     // int32 per harness contract
    const float* W       = (const float*)d_in[2];
    const float* att_src = (const float*)d_in[3];
    const float* att_dst = (const float*)d_in[4];
    const float* bias    = (const float*)d_in[5];
    const float* gamma   = (const float*)d_in[6];
    const float* beta    = (const float*)d_in[7];
    const float* res_W   = (const float*)d_in[8];
    const float* res_b   = (const float*)d_in[9];
    float* out = (float*)d_out;

    const int N_ = in_sizes[0] / 128;   // 50000
    const int E_ = in_sizes[1] / 2;     // 800000

    unsigned short* hb = (unsigned short*)d_ws;          // N*256 u16
    unsigned short* Bt = hb + (size_t)N_ * 256;          // 512*128 u16
    float* a_src  = (float*)(Bt + 512 * 128);            // N*8 f
    float* a_dst  = a_src + (size_t)N_ * 8;              // N*8 f
    int*   deg    = (int*)(a_dst + (size_t)N_ * 8);      // N int (cursor)
    int*   rowptr = deg + N_;                            // N+1 int
    int*   parts  = rowptr + N_ + 1;                     // 256 int
    int*   col    = parts + 256;                         // E int

    const int nchunk = (N_ + 255) / 256;                 // 196

    // --- CSR build ---
    hipMemsetAsync(deg, 0, (size_t)N_ * sizeof(int), stream);
    hist_kernel<<<(E_ + 255) / 256, 256, 0, stream>>>(ei, deg, E_, N_);
    scan_part_kernel<<<nchunk, 256, 0, stream>>>(deg, parts, N_);
    scan_top_kernel<<<1, 256, 0, stream>>>(parts, nchunk);
    scan_final_kernel<<<nchunk, 256, 0, stream>>>(deg, parts, rowptr, N_);
    scatter_kernel<<<(E_ + 255) / 256, 256, 0, stream>>>(ei, deg, col, E_, N_);

    // --- dense chain: pack Bt, fused GEMM(+att logits) ---
    pack_Bt_kernel<<<256, 256, 0, stream>>>(W, res_W, Bt);
    mfma_gemm_kernel<<<(N_ + 63) / 64, 256, 0, stream>>>(
        x, Bt, att_src, att_dst, res_b, hb, out, a_src, a_dst, N_);

    // --- fused gather + LN + residual + ELU ---
    gather_finalize_kernel<<<(N_ + 3) / 4, 256, 0, stream>>>(
        rowptr, col, hb, a_src, a_dst, bias, gamma, beta, out, N_);
}